// Round 2
// baseline (11817.058 us; speedup 1.0000x reference)
//
#include <hip/hip_runtime.h>
#include <stdint.h>

// RSSM forward: B=256 T=64 O=2048 A=16 L=32 C=32 H=512 R=1024 LC=1024.
// Sequential path: gh GEMM -> GRU fuse (gx inlined via gathers) -> post MLP -> gumbel-argmax sample.
// Batched: obs-part of post_l1 (hoisted), prior/dec/rew MLPs (after loop, over 16384 rows).
// PRNG: JAX threefry2x32, partitionable scheme (flip macro below if mismatch).
#define JAX_PARTITIONABLE 1

#define OFF_LAT  0L
#define OFF_HID  16777216L
#define OFF_PLOG 33554432L
#define OFF_QLOG 50331648L
#define OFF_REC  67108864L
#define OFF_REW  100663296L

// ---------------- threefry2x32 (JAX-compatible, 20 rounds) ----------------
__host__ __device__ inline uint32_t rotl32(uint32_t x, int r){ return (x<<r)|(x>>(32-r)); }

__host__ __device__ inline void tf2x32(uint32_t k0, uint32_t k1, uint32_t x0, uint32_t x1,
                                       uint32_t& o0, uint32_t& o1){
  uint32_t ks2 = k0 ^ k1 ^ 0x1BD11BDAu;
  x0 += k0; x1 += k1;
#define TFR(r) { x0 += x1; x1 = rotl32(x1,(r)); x1 ^= x0; }
  TFR(13) TFR(15) TFR(26) TFR(6)   x0 += k1;  x1 += ks2 + 1u;
  TFR(17) TFR(29) TFR(16) TFR(24)  x0 += ks2; x1 += k0 + 2u;
  TFR(13) TFR(15) TFR(26) TFR(6)   x0 += k0;  x1 += k1 + 3u;
  TFR(17) TFR(29) TFR(16) TFR(24)  x0 += k1;  x1 += ks2 + 4u;
  TFR(13) TFR(15) TFR(26) TFR(6)   x0 += ks2; x1 += k0 + 5u;
#undef TFR
  o0 = x0; o1 = x1;
}

// ---------------- generic tiled fp32 GEMM: C[M,N] = A[M,K] @ B[N,K]^T (+bias +add, relu) ----
// grid: (N/64, M/64), block 256. K % 16 == 0, M,N % 64 == 0. Deterministic ascending-k sum.
template<bool RELU, bool HAS_BIAS, bool HAS_ADD>
__global__ __launch_bounds__(256)
void gemm_bt(const float* __restrict__ A, int lda,
             const float* __restrict__ B, int ldb,
             float* __restrict__ C, long ldc,
             const float* __restrict__ bias,
             const float* __restrict__ add, long ldadd,
             int K)
{
  __shared__ float As[16][64];
  __shared__ float Bs[16][64];
  const int bm = blockIdx.y * 64;
  const int bn = blockIdx.x * 64;
  const int tid = threadIdx.x;
  const int tx = tid & 15;       // output col group
  const int ty = tid >> 4;       // output row group
  const int lrow = tid >> 2;     // 0..63 tile row for loads
  const int lc4  = (tid & 3) << 2;
  const float* Aload = A + (long)(bm + lrow) * lda + lc4;
  const float* Bload = B + (long)(bn + lrow) * ldb + lc4;
  float acc[4][4] = {};
  for (int k0 = 0; k0 < K; k0 += 16) {
    const float4 av = *reinterpret_cast<const float4*>(Aload + k0);
    const float4 bv = *reinterpret_cast<const float4*>(Bload + k0);
    __syncthreads();
    As[lc4+0][lrow]=av.x; As[lc4+1][lrow]=av.y; As[lc4+2][lrow]=av.z; As[lc4+3][lrow]=av.w;
    Bs[lc4+0][lrow]=bv.x; Bs[lc4+1][lrow]=bv.y; Bs[lc4+2][lrow]=bv.z; Bs[lc4+3][lrow]=bv.w;
    __syncthreads();
#pragma unroll
    for (int kk = 0; kk < 16; ++kk) {
      const float4 a4 = *reinterpret_cast<const float4*>(&As[kk][ty << 2]);
      const float4 b4 = *reinterpret_cast<const float4*>(&Bs[kk][tx << 2]);
      const float af[4] = {a4.x, a4.y, a4.z, a4.w};
      const float bf[4] = {b4.x, b4.y, b4.z, b4.w};
#pragma unroll
      for (int i = 0; i < 4; ++i)
#pragma unroll
        for (int j = 0; j < 4; ++j) acc[i][j] += af[i] * bf[j];
    }
  }
#pragma unroll
  for (int i = 0; i < 4; ++i) {
    const int row = bm + (ty << 2) + i;
#pragma unroll
    for (int j = 0; j < 4; ++j) {
      const int col = bn + (tx << 2) + j;
      float v = acc[i][j];
      if (HAS_BIAS) v += bias[col];
      if (HAS_ADD)  v += add[(long)row * ldadd + col];
      if (RELU)     v = fmaxf(v, 0.f);
      C[(long)row * ldc + col] = v;
    }
  }
}

// ---------------- transpose: out[C][R] = in[R][C] (arbitrary ld, bounds-checked) ----------
__global__ void transpose_kernel(const float* __restrict__ in, int ldin,
                                 float* __restrict__ out, int ldout, int R, int C)
{
  __shared__ float tile[32][33];
  const int r0 = blockIdx.y * 32, c0 = blockIdx.x * 32;
  for (int i = threadIdx.y; i < 32; i += 8) {
    const int r = r0 + i, c = c0 + threadIdx.x;
    if (r < R && c < C) tile[i][threadIdx.x] = in[(long)r * ldin + c];
  }
  __syncthreads();
  for (int i = threadIdx.y; i < 32; i += 8) {
    const int c = c0 + i, r = r0 + threadIdx.x;
    if (r < R && c < C) out[(long)c * ldout + r] = tile[threadIdx.x][i];
  }
}

__global__ void zero_kernel(float* p, int n) {
  const int i = blockIdx.x * 256 + threadIdx.x;
  if (i < n) p[i] = 0.f;
}

// ---------------- GRU fuse: gx (bias + action + one-hot gathers) inline; update h -------
// grid (4, 256): blockIdx.y = b, i = blockIdx.x*256+tid in [0,1024)
__global__ __launch_bounds__(256)
void gru_fuse_kernel(const float* __restrict__ gh, float* __restrict__ h,
                     const float* __restrict__ w_ihT /*[1040][3072]*/,
                     const float* __restrict__ b_ih,
                     const float* __restrict__ action_prev /* +(t-1)*16, stride 1024; null t=0 */,
                     const int* __restrict__ ind_prev /*[256][32]; null t=0*/,
                     float* __restrict__ hidden_out /* +t*1024, stride 65536 */)
{
  const int b = blockIdx.y;
  const int i = blockIdx.x * 256 + threadIdx.x;
  __shared__ float sa[16];
  __shared__ int   si[32];
  if (threadIdx.x < 16) sa[threadIdx.x] = action_prev ? action_prev[(long)b * 1024 + threadIdx.x] : 0.f;
  if (threadIdx.x >= 32 && threadIdx.x < 64) {
    const int l = threadIdx.x - 32;
    si[l] = ind_prev ? ind_prev[b * 32 + l] : 0;
  }
  __syncthreads();
  float xr = b_ih[i], xz = b_ih[1024 + i], xn = b_ih[2048 + i];
  if (action_prev) {
#pragma unroll
    for (int k = 0; k < 16; ++k) {
      const float a = sa[k];
      const float* wr = w_ihT + (long)k * 3072;
      xr += a * wr[i]; xz += a * wr[1024 + i]; xn += a * wr[2048 + i];
    }
  }
  if (ind_prev) {
#pragma unroll 4
    for (int l = 0; l < 32; ++l) {
      const float* wr = w_ihT + (long)(16 + l * 32 + si[l]) * 3072;
      xr += wr[i]; xz += wr[1024 + i]; xn += wr[2048 + i];
    }
  }
  const long o = (long)b * 3072;
  const float hr_ = gh[o + i], hz = gh[o + 1024 + i], hn = gh[o + 2048 + i];
  const float r = 1.f / (1.f + expf(-(xr + hr_)));
  const float z = 1.f / (1.f + expf(-(xz + hz)));
  const float n = tanhf(xn + r * hn);
  const float hold = h[(long)b * 1024 + i];
  const float hnew = (1.f - z) * n + z * hold;
  h[(long)b * 1024 + i] = hnew;
  hidden_out[(long)b * 65536 + i] = hnew;
}

// ---------------- gumbel-argmax categorical sampling (bit-exact JAX threefry) -----------
// 1024 blocks x 256: tid = (b*32+l)*32 + c; 32-lane group argmax.
__global__ __launch_bounds__(256)
void sample_kernel(const float* __restrict__ qlog /* +t*1024, stride 65536 */,
                   float* __restrict__ latent_out /* +t*1024, stride 65536 */,
                   int* __restrict__ ind_out /*[256][32]*/,
                   uint32_t key0, uint32_t key1)
{
  const unsigned tid = blockIdx.x * 256 + threadIdx.x;  // 0..262143
  const int c = tid & 31;
  const int l = (tid >> 5) & 31;
  const int b = tid >> 10;
  uint32_t y0, y1, bits;
#if JAX_PARTITIONABLE
  tf2x32(key0, key1, 0u, tid, y0, y1);
  bits = y0 ^ y1;
#else
  if (tid < 131072u) { tf2x32(key0, key1, tid, tid + 131072u, y0, y1); bits = y0; }
  else               { tf2x32(key0, key1, tid - 131072u, tid, y0, y1); bits = y1; }
#endif
  const float f = __uint_as_float((bits >> 9) | 0x3F800000u) - 1.0f;
  const float u = fmaxf(f, 1.17549435e-38f);
  const float il = (float)log((double)u);          // correctly-rounded f32 log
  const float ol = (float)log((double)(-il));
  const float g = -ol;
  const float val = g + qlog[(long)b * 65536 + l * 32 + c];
  float best = val; int bi = c;
#pragma unroll
  for (int m = 16; m; m >>= 1) {
    const float ov = __shfl_xor(best, m, 32);
    const int   oi = __shfl_xor(bi, m, 32);
    if (ov > best || (ov == best && oi < bi)) { best = ov; bi = oi; }
  }
  latent_out[(long)b * 65536 + l * 32 + c] = (c == bi) ? 1.0f : 0.0f;
  if (c == 0) ind_out[b * 32 + l] = bi;
}

// ---------------- add latent-gather + bias, relu (in-place on [16384][512] pre-act) -----
// grid (16384, 2): blockIdx.x = row r (= b*64+t), blockIdx.y*256+tid = col
__global__ __launch_bounds__(256)
void gather_relu_kernel(float* __restrict__ X, const float* __restrict__ WT /*[1024][512]*/,
                        const float* __restrict__ bias, const int* __restrict__ ind_all)
{
  const int r = blockIdx.x;
  const int col = blockIdx.y * 256 + threadIdx.x;
  const int t = r & 63, b = r >> 6;
  __shared__ int si[32];
  if (threadIdx.x < 32) si[threadIdx.x] = ind_all[(t * 256 + b) * 32 + threadIdx.x];
  __syncthreads();
  float v = X[(long)r * 512 + col] + bias[col];
#pragma unroll 8
  for (int l = 0; l < 32; ++l) v += WT[(long)(l * 32 + si[l]) * 512 + col];
  X[(long)r * 512 + col] = fmaxf(v, 0.f);
}

// ---------------- reward layer 2: out[r] = dot(hr[r,:512], w) + b ----------------------
__global__ __launch_bounds__(256)
void rew_l2_kernel(const float* __restrict__ hr, const float* __restrict__ w,
                   const float* __restrict__ b2, float* __restrict__ out)
{
  const int r = blockIdx.x * 4 + (threadIdx.x >> 6);
  const int lane = threadIdx.x & 63;
  const float* row = hr + (long)r * 512;
  float v = 0.f;
#pragma unroll
  for (int u = 0; u < 8; ++u) v += row[lane + u * 64] * w[lane + u * 64];
#pragma unroll
  for (int m = 32; m; m >>= 1) v += __shfl_down(v, m, 64);
  if (lane == 0) out[r] = v + b2[0];
}

// =======================================================================================
extern "C" void kernel_launch(void* const* d_in, const int* in_sizes, int n_in,
                              void* d_out, int out_size, void* d_ws, size_t ws_size,
                              hipStream_t stream)
{
  (void)in_sizes; (void)n_in; (void)out_size; (void)ws_size;
  const float* obs      = (const float*)d_in[0];
  const float* action   = (const float*)d_in[1];
  const float* w_ih     = (const float*)d_in[2];
  const float* w_hh     = (const float*)d_in[3];
  const float* b_ih     = (const float*)d_in[4];
  const float* b_hh     = (const float*)d_in[5];
  const float* prior_w1 = (const float*)d_in[6];
  const float* prior_b1 = (const float*)d_in[7];
  const float* prior_w2 = (const float*)d_in[8];
  const float* prior_b2 = (const float*)d_in[9];
  const float* post_w1  = (const float*)d_in[10];
  const float* post_b1  = (const float*)d_in[11];
  const float* post_w2  = (const float*)d_in[12];
  const float* post_b2  = (const float*)d_in[13];
  const float* dec_w1   = (const float*)d_in[14];
  const float* dec_b1   = (const float*)d_in[15];
  const float* dec_w2   = (const float*)d_in[16];
  const float* dec_b2   = (const float*)d_in[17];
  const float* rew_w1   = (const float*)d_in[18];
  const float* rew_b1   = (const float*)d_in[19];
  const float* rew_w2   = (const float*)d_in[20];
  const float* rew_b2   = (const float*)d_in[21];
  float* out = (float*)d_out;

  // workspace layout (floats); total ~54.7 MB
  float* wsf      = (float*)d_ws;
  float* w_ihT    = wsf;                    // [1040][3072]
  float* dec_latT = w_ihT + 3194880;        // [1024][512]
  float* rew_latT = dec_latT + 524288;      // [1024][512]
  float* h        = rew_latT + 524288;      // [256][1024]
  float* gh       = h + 262144;             // [256][3072]
  float* h1       = gh + 786432;            // [256][512]
  float* obs_part = h1 + 131072;            // [16384][512] (reused as mlpbuf after loop)
  float* mlpbuf   = obs_part;
  int*   ind_all  = (int*)(obs_part + 8388608);  // [64][256][32]

  // ---- host: derive per-step keys (pure CPU, deterministic) ----
  uint32_t key[64][2];
#if JAX_PARTITIONABLE
  for (uint32_t t = 0; t < 64; ++t) tf2x32(0u, 42u, 0u, t, key[t][0], key[t][1]);
#else
  {
    uint32_t bits[128];
    for (uint32_t i = 0; i < 64; ++i) tf2x32(0u, 42u, i, 64u + i, bits[i], bits[64 + i]);
    for (int t = 0; t < 64; ++t) { key[t][0] = bits[2 * t]; key[t][1] = bits[2 * t + 1]; }
  }
#endif

  const dim3 blk256(256), blkT(32, 8);

  // ---- pre-loop: transposes, h=0, obs-part of post layer 1 ----
  transpose_kernel<<<dim3((1040 + 31) / 32, (3072 + 31) / 32), blkT, 0, stream>>>(
      w_ih, 1040, w_ihT, 3072, 3072, 1040);
  transpose_kernel<<<dim3((1024 + 31) / 32, (512 + 31) / 32), blkT, 0, stream>>>(
      dec_w1 + 1024, 2048, dec_latT, 512, 512, 1024);
  transpose_kernel<<<dim3((1024 + 31) / 32, (512 + 31) / 32), blkT, 0, stream>>>(
      rew_w1 + 1024, 2048, rew_latT, 512, 512, 1024);
  zero_kernel<<<1024, blk256, 0, stream>>>(h, 262144);
  gemm_bt<false, false, false><<<dim3(512 / 64, 16384 / 64), blk256, 0, stream>>>(
      obs, 2048, post_w1 + 1024, 3072, obs_part, 512, nullptr, nullptr, 0, 2048);

  // ---- sequential recurrence ----
  for (int t = 0; t < 64; ++t) {
    // gh = h @ w_hh^T + b_hh
    gemm_bt<false, true, false><<<dim3(3072 / 64, 256 / 64), blk256, 0, stream>>>(
        h, 1024, w_hh, 1024, gh, 3072, b_hh, nullptr, 0, 1024);
    // GRU update (gx inlined), writes h and hidden[:,t,:]
    gru_fuse_kernel<<<dim3(4, 256), blk256, 0, stream>>>(
        gh, h, w_ihT, b_ih,
        t ? (action + (long)(t - 1) * 16) : nullptr,
        t ? (ind_all + (long)(t - 1) * 8192) : nullptr,
        out + OFF_HID + (long)t * 1024);
    // post layer 1: relu(h @ W_h^T + obs_part + b1)
    gemm_bt<true, true, true><<<dim3(512 / 64, 256 / 64), blk256, 0, stream>>>(
        h, 1024, post_w1, 3072, h1, 512, post_b1, obs_part + (long)t * 512, 32768, 1024);
    // post layer 2 -> qlog output
    gemm_bt<false, true, false><<<dim3(1024 / 64, 256 / 64), blk256, 0, stream>>>(
        h1, 512, post_w2, 512, out + OFF_QLOG + (long)t * 1024, 65536, post_b2, nullptr, 0, 512);
    // sample categorical -> latent output + indices
    sample_kernel<<<1024, blk256, 0, stream>>>(
        out + OFF_QLOG + (long)t * 1024, out + OFF_LAT + (long)t * 1024,
        ind_all + (long)t * 8192, key[t][0], key[t][1]);
  }

  // ---- batched heads over all 16384 (b,t) rows ----
  // prior
  gemm_bt<true, true, false><<<dim3(512 / 64, 16384 / 64), blk256, 0, stream>>>(
      out + OFF_HID, 1024, prior_w1, 1024, mlpbuf, 512, prior_b1, nullptr, 0, 1024);
  gemm_bt<false, true, false><<<dim3(1024 / 64, 16384 / 64), blk256, 0, stream>>>(
      mlpbuf, 512, prior_w2, 512, out + OFF_PLOG, 1024, prior_b2, nullptr, 0, 512);
  // decoder
  gemm_bt<false, false, false><<<dim3(512 / 64, 16384 / 64), blk256, 0, stream>>>(
      out + OFF_HID, 1024, dec_w1, 2048, mlpbuf, 512, nullptr, nullptr, 0, 1024);
  gather_relu_kernel<<<dim3(16384, 2), blk256, 0, stream>>>(mlpbuf, dec_latT, dec_b1, ind_all);
  gemm_bt<false, true, false><<<dim3(2048 / 64, 16384 / 64), blk256, 0, stream>>>(
      mlpbuf, 512, dec_w2, 512, out + OFF_REC, 2048, dec_b2, nullptr, 0, 512);
  // reward
  gemm_bt<false, false, false><<<dim3(512 / 64, 16384 / 64), blk256, 0, stream>>>(
      out + OFF_HID, 1024, rew_w1, 2048, mlpbuf, 512, nullptr, nullptr, 0, 1024);
  gather_relu_kernel<<<dim3(16384, 2), blk256, 0, stream>>>(mlpbuf, rew_latT, rew_b1, ind_all);
  rew_l2_kernel<<<4096, blk256, 0, stream>>>(mlpbuf, rew_w2, rew_b2, out + OFF_REW);
}